// Round 15
// baseline (162.263 us; speedup 1.0000x reference)
//
#include <hip/hip_runtime.h>
#include <hip/hip_bf16.h>
#include <stdint.h>

typedef __attribute__((ext_vector_type(4))) float f32x4;
typedef __attribute__((ext_vector_type(8))) __bf16 bf16x8;
typedef __attribute__((ext_vector_type(8))) unsigned short ushort8;

#define DEV static __device__ __forceinline__

// scratch: xn|Z|Yt|S|WqT|WkT|WvT|Wo|Mt|W4|w|rsum|bb|c  (~96.5 MB)
__device__ __align__(4096) unsigned char g_scratch[96600064];

DEV unsigned short f2bf(float f) {
  union { float f; uint32_t u; } x; x.f = f;
  uint32_t u = x.u;
  uint32_t r = (u + 0x7fffu + ((u >> 16) & 1u)) >> 16;  // RNE
  return (unsigned short)r;
}
DEV float bf2f(unsigned short b) {
  union { uint32_t u; float f; } x; x.u = ((uint32_t)b) << 16;
  return x.f;
}

DEV void gload16(const void* g, void* l) {
  __builtin_amdgcn_global_load_lds((const __attribute__((address_space(1))) void*)g,
                                   (__attribute__((address_space(3))) void*)l,
                                   16, 0, 0);
}

// XOR swizzle on byte offsets within a [rows][128 bytes] region (involution).
DEV int swz(int b) { return b ^ (((b >> 7) & 7) << 4); }

// Verified m97-structure K-loop: 128x128 tile, BK=64, 16x16x32 MFMA,
// swizzled LDS, width-16 global_load_lds. acc[4][4] f32x4 per wave.
DEV void gemm_core(const unsigned short* a_t, const unsigned short* b_t,
                   int ldA, int ldB, int K, unsigned short* lds, int tid,
                   const int* aOff, const int* bOff, f32x4 acc[4][4])
{
  for (int kt = 0; kt < K; kt += 64) {
#pragma unroll
    for (int i = 0; i < 4; ++i) {
      int o = i * 4096 + tid * 16;
      int p = swz(o);
      int row = p >> 7;
      int ce  = (p & 127) >> 1;
      gload16(a_t + (size_t)row * ldA + (kt + ce), (char*)lds + o);
      gload16(b_t + (size_t)row * ldB + (kt + ce), (char*)lds + 16384 + o);
    }
    __syncthreads();
#pragma unroll
    for (int h = 0; h < 2; ++h) {
      bf16x8 av[4], bv4[4];
#pragma unroll
      for (int m = 0; m < 4; ++m)
        av[m] = *(const bf16x8*)((const char*)lds + (aOff[m] ^ (h << 6)));
#pragma unroll
      for (int n = 0; n < 4; ++n)
        bv4[n] = *(const bf16x8*)((const char*)lds + (bOff[n] ^ (h << 6)));
#pragma unroll
      for (int m = 0; m < 4; ++m)
#pragma unroll
        for (int n = 0; n < 4; ++n)
          acc[m][n] = __builtin_amdgcn_mfma_f32_16x16x32_bf16(av[m], bv4[n], acc[m][n], 0, 0, 0);
    }
    __syncthreads();
  }
}

DEV void frag_offsets(int lane, int wm, int wn, int* aOff, int* bOff)
{
#pragma unroll
  for (int m = 0; m < 4; ++m) {
    int ar = wm + m * 16 + (lane & 15);
    aOff[m] = (ar * 128 + ((lane >> 4) * 16)) ^ ((ar & 7) << 4);
    int br = wn + m * 16 + (lane & 15);
    bOff[m] = ((br * 128 + ((lane >> 4) * 16)) ^ ((br & 7) << 4)) + 16384;
  }
}

// Coalesced readback of a 128x128 bf16 tile staged in LDS with
// byte ^= (row&12)<<3 swizzle: each wave stores 32 rows as 256B runs.
DEV void tile_readback(const char* lb, unsigned short* dst, size_t ldC,
                       int wave, int lane)
{
#pragma unroll
  for (int j = 0; j < 8; ++j) {
    int row_l = wave * 32 + (lane >> 4) * 8 + j;
    int byte = (row_l * 256 + (lane & 15) * 16) ^ ((row_l & 12) << 3);
    ushort8 v = *(const ushort8*)(lb + byte);
    *(ushort8*)(dst + (size_t)row_l * ldC + (lane & 15) * 8) = v;
  }
}

// ---------------------------------------------------------------------------
// G0' (8832 blocks, 1-D) -- LN merged in so it overlaps the small GEMM:
//  [0,128):    GEMM  z=b>>6: z=0 Mt=(Wk^T Wq)/32, z=1 W4=Wo Wv
//  [128,384):  cvec[d] = dot(wkT[d,:], bq)/32 (wave/d; blocks 128-131 zero rsum)
//  [384,640):  bb[e] = dot(Wo[e,:], bv) + bo[e]  (wave per e)
//  [640,8832): LayerNorm row (bid-640) -> xn   (no dep on GEMM blocks)
// ---------------------------------------------------------------------------
__global__ __launch_bounds__(256, 4)
void g0(const unsigned short* __restrict__ wkT, const unsigned short* __restrict__ wqT,
        const unsigned short* __restrict__ woB, const unsigned short* __restrict__ wvT,
        unsigned short* __restrict__ mt, unsigned short* __restrict__ w4,
        const float* __restrict__ bq, const float* __restrict__ Wo,
        const float* __restrict__ bv, const float* __restrict__ bo,
        float* __restrict__ cvec, float* __restrict__ bb, float* __restrict__ rsm,
        const float* __restrict__ x, const float* __restrict__ gamma,
        const float* __restrict__ beta, unsigned short* __restrict__ xn)
{
  __shared__ unsigned short lds[16384];
  const int bid = blockIdx.x;
  const int tid = threadIdx.x, lane = tid & 63, wave = tid >> 6;

  if (bid >= 640) {  // ---- LayerNorm row ----
    const int row = bid - 640;
    float* red1 = (float*)lds;
    float* red2 = (float*)lds + 4;
    const float4 xv = ((const float4*)(x + (size_t)row * 1024))[tid];
    float s = xv.x + xv.y + xv.z + xv.w;
#pragma unroll
    for (int d = 1; d < 64; d <<= 1) s += __shfl_xor(s, d);
    if (lane == 0) red1[wave] = s;
    __syncthreads();
    const float mu = (red1[0] + red1[1] + red1[2] + red1[3]) * (1.0f / 1024.0f);
    float4 dv;
    dv.x = xv.x - mu; dv.y = xv.y - mu; dv.z = xv.z - mu; dv.w = xv.w - mu;
    float vs = dv.x * dv.x + dv.y * dv.y + dv.z * dv.z + dv.w * dv.w;
#pragma unroll
    for (int d = 1; d < 64; d <<= 1) vs += __shfl_xor(vs, d);
    if (lane == 0) red2[wave] = vs;
    __syncthreads();
    const float var = (red2[0] + red2[1] + red2[2] + red2[3]) * (1.0f / 1024.0f);
    const float rs = rsqrtf(var + 1e-5f);
    const float4 g = ((const float4*)gamma)[tid];
    const float4 b = ((const float4*)beta)[tid];
    ushort4 o;
    o.x = f2bf(dv.x * rs * g.x + b.x);
    o.y = f2bf(dv.y * rs * g.y + b.y);
    o.z = f2bf(dv.z * rs * g.z + b.z);
    o.w = f2bf(dv.w * rs * g.w + b.w);
    ((ushort4*)(xn + (size_t)row * 1024))[tid] = o;
    return;
  }

  if (bid >= 128) {  // ---- aux: cvec / bb / rsum-zero ----
    const int b2 = bid - 128;
    if (b2 < 256) {
      if (b2 < 4) {
        const int i2 = (b2 * 256 + tid) * 2;
        ((float4*)rsm)[i2] = make_float4(0.f, 0.f, 0.f, 0.f);
        ((float4*)rsm)[i2 + 1] = make_float4(0.f, 0.f, 0.f, 0.f);
      }
      const int d = b2 * 4 + wave;
      float s = 0.f;
#pragma unroll
      for (int q = 0; q < 2; ++q) {
        ushort8 v = *(const ushort8*)(wkT + (size_t)d * 1024 + lane * 16 + q * 8);
#pragma unroll
        for (int k = 0; k < 8; ++k)
          s += bf2f(v[k]) * bq[lane * 16 + q * 8 + k];
      }
#pragma unroll
      for (int dd = 1; dd < 64; dd <<= 1) s += __shfl_xor(s, dd);
      if (lane == 0) cvec[d] = s * 0.03125f;
    } else {
      const int e = (b2 - 256) * 4 + wave;
      float s = 0.f;
#pragma unroll
      for (int q = 0; q < 4; ++q) {
        float4 a = *(const float4*)(Wo + (size_t)e * 1024 + lane * 16 + q * 4);
        float4 b = *(const float4*)(bv + lane * 16 + q * 4);
        s += a.x * b.x + a.y * b.y + a.z * b.z + a.w * b.w;
      }
#pragma unroll
      for (int dd = 1; dd < 64; dd <<= 1) s += __shfl_xor(s, dd);
      if (lane == 0) bb[e] = s + bo[e];
    }
    return;
  }

  // ---- GEMM: Mt / W4 ----
  const int z = bid >> 6;
  const int idx = bid & 63;
  const int m0 = (idx >> 3) * 128, n0 = (idx & 7) * 128;
  const int wm = (wave >> 1) * 64, wn = (wave & 1) * 64;
  int aOff[4], bOff[4];
  frag_offsets(lane, wm, wn, aOff, bOff);
  f32x4 acc[4][4] = {};
  const unsigned short* a_t = (z == 0) ? (wkT + (size_t)m0 * 1024) : (woB + (size_t)m0 * 1024);
  const unsigned short* b_t = (z == 0) ? (wqT + (size_t)n0 * 1024) : (wvT + (size_t)n0 * 1024);
  gemm_core(a_t, b_t, 1024, 1024, 1024, lds, tid, aOff, bOff, acc);

  const int r0 = (lane >> 4) * 4, cL = lane & 15;
  const float scale = (z == 0) ? 0.03125f : 1.0f;
  unsigned short* Cp = (z == 0) ? mt : w4;
#pragma unroll
  for (int n = 0; n < 4; ++n) {
    int colg = n0 + wn + n * 16 + cL;
#pragma unroll
    for (int m = 0; m < 4; ++m) {
      int rowg = m0 + wm + m * 16 + r0;
#pragma unroll
      for (int i = 0; i < 4; ++i)
        Cp[(size_t)(rowg + i) * 1024 + colg] = f2bf(acc[m][n][i] * scale);
    }
  }
}

// ---------------------------------------------------------------------------
// G1: z=0: Z  = xn @ Mt^T  (LDS-transposed coalesced store)
//     z=1: Yt = (xn @ W4^T)^T per-batch store  [= (V-b) Wo^T transposed]
//     z=2: w_j = xn_j . cvec  (wave per row, 512 blocks x 16 rows)
// ---------------------------------------------------------------------------
__global__ __launch_bounds__(256, 4)
void g1(const unsigned short* __restrict__ xn, const unsigned short* __restrict__ mt,
        const unsigned short* __restrict__ w4, unsigned short* __restrict__ Z,
        unsigned short* __restrict__ yt, const float* __restrict__ cvec,
        float* __restrict__ w)
{
  __shared__ unsigned short lds[16384];
  const int tid = threadIdx.x, lane = tid & 63, wave = tid >> 6;
  const int z = blockIdx.z;

  if (z == 2) {
    const int flat = blockIdx.y * 64 + blockIdx.x;   // 0..511
#pragma unroll
    for (int p = 0; p < 4; ++p) {
      const int j = flat * 16 + wave * 4 + p;
      float s = 0.f;
#pragma unroll
      for (int q = 0; q < 2; ++q) {
        ushort8 v = *(const ushort8*)(xn + (size_t)j * 1024 + lane * 16 + q * 8);
#pragma unroll
        for (int k = 0; k < 8; ++k)
          s += bf2f(v[k]) * cvec[lane * 16 + q * 8 + k];
      }
#pragma unroll
      for (int d = 1; d < 64; d <<= 1) s += __shfl_xor(s, d);
      if (lane == 0) w[j] = s;
    }
    return;
  }

  const int m0 = blockIdx.x * 128, n0 = blockIdx.y * 128;
  const int wm = (wave >> 1) * 64, wn = (wave & 1) * 64;
  int aOff[4], bOff[4];
  frag_offsets(lane, wm, wn, aOff, bOff);
  f32x4 acc[4][4] = {};
  const unsigned short* b_t = ((z == 0) ? mt : w4) + (size_t)n0 * 1024;
  gemm_core(xn + (size_t)m0 * 1024, b_t, 1024, 1024, 1024, lds, tid, aOff, bOff, acc);

  const int r0 = (lane >> 4) * 4, cL = lane & 15;
  if (z == 0) {
    char* lb = (char*)lds;
#pragma unroll
    for (int n = 0; n < 4; ++n) {
      int col_l = wn + n * 16 + cL;
#pragma unroll
      for (int m = 0; m < 4; ++m)
#pragma unroll
        for (int i = 0; i < 4; ++i) {
          int row_l = wm + m * 16 + r0 + i;
          int byte = (row_l * 256 + col_l * 2) ^ ((row_l & 12) << 3);
          *(unsigned short*)(lb + byte) = f2bf(acc[m][n][i]);
        }
    }
    __syncthreads();
    tile_readback(lb, Z + (size_t)m0 * 1024 + n0, 1024, wave, lane);
  } else {
#pragma unroll
    for (int n = 0; n < 4; ++n) {
      int colg = n0 + wn + n * 16 + cL;
#pragma unroll
      for (int m = 0; m < 4; ++m) {
        int rowg = m0 + wm + m * 16 + r0;
        int bat = rowg >> 11, sdx = rowg & 2047;
        ushort4 pk;
        pk.x = f2bf(acc[m][n][0]);
        pk.y = f2bf(acc[m][n][1]);
        pk.z = f2bf(acc[m][n][2]);
        pk.w = f2bf(acc[m][n][3]);
        *(ushort4*)(yt + (size_t)bat * 2097152 + (size_t)colg * 2048 + sdx) = pk;
      }
    }
  }
}

// ---------------------------------------------------------------------------
// G2f: 256x256-tile 8-phase counted-vmcnt scores GEMM (round-3 loop, which
// refcheck'd correct; now with __launch_bounds__(512,1) -- the (512,2) cap of
// rounds 2/3 pinned VGPR at 128 = acc alone -> catastrophic spill (WRITE_SIZE
// +30MB scratch evidence). 128 KiB LDS => 1 block/CU anyway; give 512 VGPR.
// P' = exp(Z[b] @ xn[b]^T + w_col - 12), rsum atomics, S scatter.
// ---------------------------------------------------------------------------
__global__ __launch_bounds__(512, 1)
void g2f(const unsigned short* __restrict__ Z, const unsigned short* __restrict__ xn,
         unsigned short* __restrict__ S, const float* __restrict__ w,
         float* __restrict__ rsum)
{
  extern __shared__ char lds[];
  const int tid  = threadIdx.x;
  const int lane = tid & 63;
  const int wave = tid >> 6;
  const int wr = wave >> 2;   // 0..1 -> rows wr*128..+127
  const int wc = wave & 3;    // 0..3 -> cols wc*64..+63
  const int z  = blockIdx.z;
  const int m0 = blockIdx.x * 256;
  const int n0 = blockIdx.y * 256;
  const int K  = 1024, ldA = 1024, ldB = 1024;
  const unsigned short* a_t = Z  + (size_t)z * 2097152 + (size_t)m0 * ldA;
  const unsigned short* b_t = xn + (size_t)z * 2097152 + (size_t)n0 * ldB;

  // stage constants: linear LDS dest + inverse-swizzled global source
  const int so0 = tid * 16;        const int sp0 = swz(so0);
  const int sr0 = sp0 >> 7, sc0 = (sp0 & 127) >> 1;
  const int so1 = 8192 + tid * 16; const int sp1 = swz(so1);
  const int sr1 = sp1 >> 7, sc1 = (sp1 & 127) >> 1;

  int aoff[8];
#pragma unroll
  for (int mi = 0; mi < 8; ++mi) {
    int r = mi * 16 + (lane & 15);
    aoff[mi] = (r * 128 + ((lane >> 4) * 16)) ^ ((r & 7) << 4);
  }
  int boff[4];
#pragma unroll
  for (int ni = 0; ni < 4; ++ni) {
    int r = (wc & 1) * 64 + ni * 16 + (lane & 15);
    boff[ni] = (r * 128 + ((lane >> 4) * 16)) ^ ((r & 7) << 4);
  }

  f32x4 acc[8][4] = {};

  auto STAGE = [&](int base, const unsigned short* src, int ld, int kc) {
    gload16(src + sr0 * ld + kc + sc0, lds + base + so0);
    gload16(src + sr1 * ld + kc + sc1, lds + base + so1);
  };

  const int NI = K >> 7;
  // prologue: t0 (B then A), t1's B.  vmcnt(4) completes t0's 8 loads.
  STAGE(32768,  b_t,             ldB, 0);
  STAGE(49152,  b_t + 128 * ldB, ldB, 0);
  STAGE(0,      a_t,             ldA, 0);
  STAGE(16384,  a_t + 128 * ldA, ldA, 0);
  STAGE(98304,  b_t,             ldB, 64);
  STAGE(114688, b_t + 128 * ldB, ldB, 64);
  asm volatile("s_waitcnt vmcnt(4)" ::: "memory");
  __builtin_amdgcn_s_barrier();

  for (int it = 0; it < NI; ++it) {
    const int kA1 = it * 128 + 64;
    int kn  = it * 128 + 128; if (kn  > K - 64) kn  = K - 64;
    int kn2 = it * 128 + 192; if (kn2 > K - 64) kn2 = K - 64;
#pragma unroll
    for (int c = 0; c < 2; ++c) {
      const char* aB = lds + c * 65536 + wr * 16384;
      const char* bB = lds + c * 65536 + 32768 + (wc >> 1) * 16384;
      bf16x8 bfr[4][2];
#pragma unroll
      for (int q = 0; q < 4; ++q) {
        const int p = c * 4 + q;
        if (q == 0) {
#pragma unroll
          for (int ni = 0; ni < 4; ++ni)
#pragma unroll
            for (int h = 0; h < 2; ++h)
              bfr[ni][h] = *(const bf16x8*)(bB + (boff[ni] ^ (h << 6)));
        }
        bf16x8 afr[2][2];
#pragma unroll
        for (int m2 = 0; m2 < 2; ++m2)
#pragma unroll
          for (int h = 0; h < 2; ++h)
            afr[m2][h] = *(const bf16x8*)(aB + (aoff[q * 2 + m2] ^ (h << 6)));
        if (p == 0)      STAGE(65536,  a_t,             ldA, kA1);
        else if (p == 1) STAGE(81920,  a_t + 128 * ldA, ldA, kA1);
        else if (p == 2) STAGE(32768,  b_t,             ldB, kn);
        else if (p == 3) STAGE(49152,  b_t + 128 * ldB, ldB, kn);
        else if (p == 4) STAGE(0,      a_t,             ldA, kn);
        else if (p == 5) STAGE(16384,  a_t + 128 * ldA, ldA, kn);
        else if (p == 6) STAGE(98304,  b_t,             ldB, kn2);
        else             STAGE(114688, b_t + 128 * ldB, ldB, kn2);
        if (q == 0) asm volatile("s_waitcnt lgkmcnt(8)" ::: "memory");
        __builtin_amdgcn_s_barrier();
        asm volatile("s_waitcnt lgkmcnt(0)" ::: "memory");
        __builtin_amdgcn_s_setprio(1);
#pragma unroll
        for (int h = 0; h < 2; ++h)
#pragma unroll
          for (int ni = 0; ni < 4; ++ni)
#pragma unroll
            for (int m2 = 0; m2 < 2; ++m2)
              acc[q * 2 + m2][ni] = __builtin_amdgcn_mfma_f32_16x16x32_bf16(
                  afr[m2][h], bfr[ni][h], acc[q * 2 + m2][ni], 0, 0, 0);
        __builtin_amdgcn_s_setprio(0);
        if (q == 3) asm volatile("s_waitcnt vmcnt(4)" ::: "memory");
        __builtin_amdgcn_s_barrier();
      }
    }
  }

  // epilogue: P' = exp(acc + w - 12); rsum partials; S scatter.
  const int r0 = (lane >> 4) * 4;
  const int cL = lane & 15;
  const int wrow = m0 + wr * 128;
  const int wcol = n0 + wc * 64;
  unsigned short* Cp = S + (size_t)z * 4194304;

  float rs[8][4];
#pragma unroll
  for (int mi = 0; mi < 8; ++mi)
#pragma unroll
    for (int i = 0; i < 4; ++i) rs[mi][i] = 0.0f;

#pragma unroll
  for (int ni = 0; ni < 4; ++ni) {
    int colg = wcol + ni * 16 + cL;
    float wv = w[(size_t)z * 2048 + colg];
#pragma unroll
    for (int mi = 0; mi < 8; ++mi) {
      int rowg = wrow + mi * 16 + r0;
#pragma unroll
      for (int i = 0; i < 4; ++i) {
        float p = __expf(acc[mi][ni][i] + wv - 12.0f);
        rs[mi][i] += p;
        Cp[(size_t)(rowg + i) * 2048 + colg] = f2bf(p);
      }
    }
  }
#pragma unroll
  for (int mi = 0; mi < 8; ++mi)
#pragma unroll
    for (int i = 0; i < 4; ++i) {
      float v = rs[mi][i];
      v += __shfl_xor(v, 1);
      v += __shfl_xor(v, 2);
      v += __shfl_xor(v, 4);
      v += __shfl_xor(v, 8);
      if (cL == 0)
        atomicAdd(&rsum[(size_t)z * 2048 + wrow + mi * 16 + r0 + i], v);
    }
}

// ---------------------------------------------------------------------------
// G2 fallback (128^2, round-14 version) -- used if 128KiB LDS attr fails.
// ---------------------------------------------------------------------------
__global__ __launch_bounds__(256, 4)
void g2(const unsigned short* __restrict__ Z, const unsigned short* __restrict__ xn,
        unsigned short* __restrict__ S, const float* __restrict__ w,
        float* __restrict__ rsum)
{
  __shared__ unsigned short lds[16384];
  const int tid = threadIdx.x, lane = tid & 63, wave = tid >> 6;
  const int z = blockIdx.z;
  const int m0 = blockIdx.x * 128, n0 = blockIdx.y * 128;
  const int wm = (wave >> 1) * 64, wn = (wave & 1) * 64;
  int aOff[4], bOff[4];
  frag_offsets(lane, wm, wn, aOff, bOff);
  f32x4 acc[4][4] = {};
  gemm_core(Z + (size_t)z * 2097152 + (size_t)m0 * 1024,
            xn + (size_t)z * 2097152 + (size_t)n0 * 1024,
            1024, 1024, 1024, lds, tid, aOff, bOff, acc);

  const int r0 = (lane >> 4) * 4, cL = lane & 15;
  char* lb = (char*)lds;
  float rs[4][4];
#pragma unroll
  for (int m = 0; m < 4; ++m)
#pragma unroll
    for (int i = 0; i < 4; ++i) rs[m][i] = 0.0f;
#pragma unroll
  for (int n = 0; n < 4; ++n) {
    int col_l = wn + n * 16 + cL;
    float wv = w[(size_t)z * 2048 + n0 + col_l];
#pragma unroll
    for (int m = 0; m < 4; ++m) {
#pragma unroll
      for (int i = 0; i < 4; ++i) {
        int row_l = wm + m * 16 + r0 + i;
        float p = __expf(acc[m][n][i] + wv - 12.0f);
        rs[m][i] += p;
        int byte = (row_l * 256 + col_l * 2) ^ ((row_l & 12) << 3);
        *(unsigned short*)(lb + byte) = f2bf(p);
      }
    }
  }
#pragma unroll
  for (int m = 0; m < 4; ++m)
#pragma unroll
    for (int i = 0; i < 4; ++i) {
      float v = rs[m][i];
      v += __shfl_xor(v, 1);
      v += __shfl_xor(v, 2);
      v += __shfl_xor(v, 4);
      v += __shfl_xor(v, 8);
      if (cL == 0)
        atomicAdd(&rsum[(size_t)z * 2048 + m0 + wm + m * 16 + r0 + i], v);
    }
  __syncthreads();
  tile_readback(lb, S + (size_t)z * 4194304 + (size_t)m0 * 2048 + n0, 2048, wave, lane);
}

// ---------------------------------------------------------------------------
// G3: out[b] = (P'[b] @ Yt[b]^T) / rsum + bb   (fp32, K=2048)
// 64x128 tile -> 1024 blocks = 4/CU.
// ---------------------------------------------------------------------------
__global__ __launch_bounds__(256, 4)
void g3(const unsigned short* __restrict__ S, const unsigned short* __restrict__ yt,
        float* __restrict__ out, const float* __restrict__ bb,
        const float* __restrict__ rsum)
{
  __shared__ unsigned short lds[12288];
  const int tid = threadIdx.x, lane = tid & 63, wave = tid >> 6;
  const int z = blockIdx.z;
  const int m0 = blockIdx.x * 64, n0 = blockIdx.y * 128;
  const int wm = (wave >> 1) * 32, wn = (wave & 1) * 64;

  int aOff[2], bOff[4];
#pragma unroll
  for (int m = 0; m < 2; ++m) {
    int ar = wm + m * 16 + (lane & 15);
    aOff[m] = (ar * 128 + ((lane >> 4) * 16)) ^ ((ar & 7) << 4);
  }
#pragma unroll
  for (int n = 0; n < 4; ++n) {
    int br = wn + n * 16 + (lane & 15);
    bOff[n] = ((br * 128 + ((lane >> 4) * 16)) ^ ((br & 7) << 4)) + 8192;
  }

  const unsigned short* a_t = S + (size_t)z * 4194304 + (size_t)m0 * 2048;
  const unsigned short* b_t = yt + (size_t)z * 2097152 + (size_t)n0 * 2048;

  f32x4 acc[2][4] = {};

  for (int kt = 0; kt < 2048; kt += 64) {
#pragma unroll
    for (int i = 0; i < 2; ++i) {
      int rel = i * 4096 + tid * 16;
      int p = swz(rel);
      int row = p >> 7, ce = (p & 127) >> 1;
      gload16(a_t + (size_t)row * 2048 + (kt + ce), (char*)lds + rel);
    }
#pragma unroll
    for (int i = 0; i < 4; ++i) {
      int rel = i * 4096 + tid * 16;
      int p = swz(rel);
      int row = p >> 7, ce = (p & 127) >> 1;
      gload16(b_t + (size_t)row * 2048 + (kt + ce), (char*)lds + 8192 + rel);
    }
    __syncthreads();
#pragma unroll
    for (int h = 0; h < 2; ++h) {
      bf16x8 av[2], bv4[4];
#pragma unroll
      for (int m = 0; m < 2; ++m)
        av[m] = *(const bf16x8*)((const char*)lds + (aOff[m] ^ (h << 6)));
#pragma unroll
      for (int n = 0; n < 4; ++n)
        bv4[n] = *(const bf16x8*)((const char*)lds + (bOff[n] ^ (h << 6)));
#pragma unroll
      for (int m = 0; m < 2; ++m)
#pragma unroll
        for (int n = 0; n < 4; ++n)
          acc[m][n] = __builtin_amdgcn_mfma_f32_16x16x32_bf16(av[m], bv4[n], acc[m][n], 0, 0, 0);
    }
    __syncthreads();
  }

  const int r0 = (lane >> 4) * 4, cL = lane & 15;
  float* Cp = out + (size_t)z * 2097152;
#pragma unroll
  for (int m = 0; m < 2; ++m) {
    int rowg = m0 + wm + m * 16 + r0;
#pragma unroll
    for (int i = 0; i < 4; ++i) {
      float inv = 1.0f / rsum[(size_t)z * 2048 + rowg + i];
#pragma unroll
      for (int n = 0; n < 4; ++n) {
        int colg = n0 + wn + n * 16 + cL;
        Cp[(size_t)(rowg + i) * 1024 + colg] = acc[m][n][i] * inv + bb[colg];
      }
    }
  }
}

// ---------------------------------------------------------------------------
// prep': weights only. [0,512) Wo cvt; [512,1280) transpose-cvt Wq/Wk/Wv.
// ---------------------------------------------------------------------------
__global__ __launch_bounds__(256)
void prep(const float* __restrict__ Wq, const float* __restrict__ Wk,
          const float* __restrict__ Wv, const float* __restrict__ Wo,
          unsigned short* __restrict__ wqT, unsigned short* __restrict__ wkT,
          unsigned short* __restrict__ wvT, unsigned short* __restrict__ woB)
{
  __shared__ float tlds[64][65];
  const int bid = blockIdx.x;
  const int tid = threadIdx.x;

  if (bid < 512) {
    const int idx = (bid * 256 + tid) * 8;
    const float4 a = *(const float4*)(Wo + idx);
    const float4 b = *(const float4*)(Wo + idx + 4);
    ushort4 r0, r1;
    r0.x = f2bf(a.x); r0.y = f2bf(a.y); r0.z = f2bf(a.z); r0.w = f2bf(a.w);
    r1.x = f2bf(b.x); r1.y = f2bf(b.y); r1.z = f2bf(b.z); r1.w = f2bf(b.w);
    *(ushort4*)(woB + idx) = r0;
    *(ushort4*)(woB + idx + 4) = r1;
    return;
  }
  {
    const int t = bid - 512;
    const int mat = t >> 8;
    const int tile = t & 255;
    const int R0 = (tile >> 4) * 64, C0 = (tile & 15) * 64;
    const float* src = (mat == 0) ? Wq : (mat == 1) ? Wk : Wv;
    unsigned short* dst = (mat == 0) ? wqT : (mat == 1) ? wkT : wvT;
#pragma unroll
    for (int p = 0; p < 4; ++p) {
      int r = p * 16 + (tid >> 4);
      int c = (tid & 15) * 4;
      float4 v = *(const float4*)(src + (size_t)(R0 + r) * 1024 + C0 + c);
      tlds[r][c + 0] = v.x; tlds[r][c + 1] = v.y;
      tlds[r][c + 2] = v.z; tlds[r][c + 3] = v.w;
    }
    __syncthreads();
    const int c = tid >> 2;
    const int chunk = tid & 3;
    ushort8 o0, o1;
#pragma unroll
    for (int k = 0; k < 8; ++k)  o0[k] = f2bf(tlds[chunk * 16 + k][c]);
#pragma unroll
    for (int k = 0; k < 8; ++k)  o1[k] = f2bf(tlds[chunk * 16 + 8 + k][c]);
    unsigned short* dp = dst + (size_t)(C0 + c) * 1024 + R0 + chunk * 16;
    *(ushort8*)(dp) = o0;
    *(ushort8*)(dp + 8) = o1;
  }
}

// ---------------------------------------------------------------------------
extern "C" void kernel_launch(void* const* d_in, const int* in_sizes, int n_in,
                              void* d_out, int out_size, void* d_ws, size_t ws_size,
                              hipStream_t stream) {
  const float* x     = (const float*)d_in[0];
  const float* gamma = (const float*)d_in[1];
  const float* beta  = (const float*)d_in[2];
  const float* Wq    = (const float*)d_in[3];
  const float* bq    = (const float*)d_in[4];
  const float* Wk    = (const float*)d_in[5];
  const float* Wv    = (const float*)d_in[7];
  const float* bv    = (const float*)d_in[8];
  const float* Wo    = (const float*)d_in[9];
  const float* bo    = (const float*)d_in[10];

  char* ws;
  if (ws_size >= (size_t)96542720) {
    ws = (char*)d_ws;
  } else {
    void* sp = nullptr;
    hipGetSymbolAddress(&sp, HIP_SYMBOL(g_scratch));
    ws = (char*)sp;
  }

  unsigned short* xn  = (unsigned short*)(ws);              // 8192x1024 bf16
  unsigned short* Z   = (unsigned short*)(ws + 16777216);   // 8192x1024 bf16
  unsigned short* yt  = (unsigned short*)(ws + 33554432);   // 4x1024x2048 bf16
  unsigned short* S   = (unsigned short*)(ws + 50331648);   // 4x2048x2048 bf16
  unsigned short* wqT = (unsigned short*)(ws + 83886080);
  unsigned short* wkT = (unsigned short*)(ws + 85983232);
  unsigned short* wvT = (unsigned short*)(ws + 88080384);
  unsigned short* woB = (unsigned short*)(ws + 90177536);
  unsigned short* mt  = (unsigned short*)(ws + 92274688);   // (Wk^T Wq)/32
  unsigned short* w4  = (unsigned short*)(ws + 94371840);   // Wo Wv
  float*          wv_ = (float*)(ws + 96468992);            // 8192
  float*          rsm = (float*)(ws + 96501760);            // 8192
  float*          bb  = (float*)(ws + 96534528);            // 1024
  float*          cv  = (float*)(ws + 96538624);            // 1024

  int use256 =
      (hipFuncSetAttribute(reinterpret_cast<const void*>(&g2f),
                           hipFuncAttributeMaxDynamicSharedMemorySize,
                           131072) == hipSuccess);

  prep<<<1280, 256, 0, stream>>>(Wq, Wk, Wv, Wo, wqT, wkT, wvT, woB);
  g0<<<8832, 256, 0, stream>>>(wkT, wqT, woB, wvT, mt, w4,
                               bq, Wo, bv, bo, cv, bb, rsm,
                               x, gamma, beta, xn);
  g1<<<dim3(64, 8, 3), 256, 0, stream>>>(xn, mt, w4, Z, yt, cv, wv_);
  if (use256)
    g2f<<<dim3(8, 8, 4), 512, 131072, stream>>>(Z, xn, S, wv_, rsm);
  else
    g2<<<dim3(16, 16, 4), 256, 0, stream>>>(Z, xn, S, wv_, rsm);
  g3<<<dim3(32, 8, 4), 256, 0, stream>>>(S, yt, (float*)d_out, bb, rsm);
}

// Round 16
// 161.128 us; speedup vs baseline: 1.0070x; 1.0070x over previous
//
#include <hip/hip_runtime.h>
#include <hip/hip_bf16.h>
#include <stdint.h>

typedef __attribute__((ext_vector_type(4))) float f32x4;
typedef __attribute__((ext_vector_type(8))) __bf16 bf16x8;
typedef __attribute__((ext_vector_type(8))) unsigned short ushort8;

#define DEV static __device__ __forceinline__

// scratch: xn|Z|Yt|S|WqT|WkT|WvT|Wo|Mt|W4|w|rsum|bb|c  (~96.5 MB)
__device__ __align__(4096) unsigned char g_scratch[96600064];

DEV unsigned short f2bf(float f) {
  union { float f; uint32_t u; } x; x.f = f;
  uint32_t u = x.u;
  uint32_t r = (u + 0x7fffu + ((u >> 16) & 1u)) >> 16;  // RNE
  return (unsigned short)r;
}
DEV float bf2f(unsigned short b) {
  union { uint32_t u; float f; } x; x.u = ((uint32_t)b) << 16;
  return x.f;
}

DEV void gload16(const void* g, void* l) {
  __builtin_amdgcn_global_load_lds((const __attribute__((address_space(1))) void*)g,
                                   (__attribute__((address_space(3))) void*)l,
                                   16, 0, 0);
}

// XOR swizzle on byte offsets within a [rows][128 bytes] region (involution).
DEV int swz(int b) { return b ^ (((b >> 7) & 7) << 4); }

// Verified m97-structure K-loop: 128x128 tile, BK=64, 16x16x32 MFMA,
// swizzled LDS, width-16 global_load_lds. acc[4][4] f32x4 per wave.
DEV void gemm_core(const unsigned short* a_t, const unsigned short* b_t,
                   int ldA, int ldB, int K, unsigned short* lds, int tid,
                   const int* aOff, const int* bOff, f32x4 acc[4][4])
{
  for (int kt = 0; kt < K; kt += 64) {
#pragma unroll
    for (int i = 0; i < 4; ++i) {
      int o = i * 4096 + tid * 16;
      int p = swz(o);
      int row = p >> 7;
      int ce  = (p & 127) >> 1;
      gload16(a_t + (size_t)row * ldA + (kt + ce), (char*)lds + o);
      gload16(b_t + (size_t)row * ldB + (kt + ce), (char*)lds + 16384 + o);
    }
    __syncthreads();
#pragma unroll
    for (int h = 0; h < 2; ++h) {
      bf16x8 av[4], bv4[4];
#pragma unroll
      for (int m = 0; m < 4; ++m)
        av[m] = *(const bf16x8*)((const char*)lds + (aOff[m] ^ (h << 6)));
#pragma unroll
      for (int n = 0; n < 4; ++n)
        bv4[n] = *(const bf16x8*)((const char*)lds + (bOff[n] ^ (h << 6)));
#pragma unroll
      for (int m = 0; m < 4; ++m)
#pragma unroll
        for (int n = 0; n < 4; ++n)
          acc[m][n] = __builtin_amdgcn_mfma_f32_16x16x32_bf16(av[m], bv4[n], acc[m][n], 0, 0, 0);
    }
    __syncthreads();
  }
}

DEV void frag_offsets(int lane, int wm, int wn, int* aOff, int* bOff)
{
#pragma unroll
  for (int m = 0; m < 4; ++m) {
    int ar = wm + m * 16 + (lane & 15);
    aOff[m] = (ar * 128 + ((lane >> 4) * 16)) ^ ((ar & 7) << 4);
    int br = wn + m * 16 + (lane & 15);
    bOff[m] = ((br * 128 + ((lane >> 4) * 16)) ^ ((br & 7) << 4)) + 16384;
  }
}

// Coalesced readback of a 128x128 bf16 tile staged in LDS with
// byte ^= (row&12)<<3 swizzle: each wave stores 32 rows as 256B runs.
DEV void tile_readback(const char* lb, unsigned short* dst, size_t ldC,
                       int wave, int lane)
{
#pragma unroll
  for (int j = 0; j < 8; ++j) {
    int row_l = wave * 32 + (lane >> 4) * 8 + j;
    int byte = (row_l * 256 + (lane & 15) * 16) ^ ((row_l & 12) << 3);
    ushort8 v = *(const ushort8*)(lb + byte);
    *(ushort8*)(dst + (size_t)row_l * ldC + (lane & 15) * 8) = v;
  }
}

// ---------------------------------------------------------------------------
// G0' (8832 blocks, 1-D) -- LN merged in so it overlaps the small GEMM:
//  [0,128):    GEMM  z=b>>6: z=0 Mt=(Wk^T Wq)/32, z=1 W4=Wo Wv
//  [128,384):  cvec[d] = dot(wkT[d,:], bq)/32 (wave/d; blocks 128-131 zero rsum)
//  [384,640):  bb[e] = dot(Wo[e,:], bv) + bo[e]  (wave per e)
//  [640,8832): LayerNorm row (bid-640) -> xn   (no dep on GEMM blocks)
// ---------------------------------------------------------------------------
__global__ __launch_bounds__(256, 4)
void g0(const unsigned short* __restrict__ wkT, const unsigned short* __restrict__ wqT,
        const unsigned short* __restrict__ woB, const unsigned short* __restrict__ wvT,
        unsigned short* __restrict__ mt, unsigned short* __restrict__ w4,
        const float* __restrict__ bq, const float* __restrict__ Wo,
        const float* __restrict__ bv, const float* __restrict__ bo,
        float* __restrict__ cvec, float* __restrict__ bb, float* __restrict__ rsm,
        const float* __restrict__ x, const float* __restrict__ gamma,
        const float* __restrict__ beta, unsigned short* __restrict__ xn)
{
  __shared__ unsigned short lds[16384];
  const int bid = blockIdx.x;
  const int tid = threadIdx.x, lane = tid & 63, wave = tid >> 6;

  if (bid >= 640) {  // ---- LayerNorm row ----
    const int row = bid - 640;
    float* red1 = (float*)lds;
    float* red2 = (float*)lds + 4;
    const float4 xv = ((const float4*)(x + (size_t)row * 1024))[tid];
    float s = xv.x + xv.y + xv.z + xv.w;
#pragma unroll
    for (int d = 1; d < 64; d <<= 1) s += __shfl_xor(s, d);
    if (lane == 0) red1[wave] = s;
    __syncthreads();
    const float mu = (red1[0] + red1[1] + red1[2] + red1[3]) * (1.0f / 1024.0f);
    float4 dv;
    dv.x = xv.x - mu; dv.y = xv.y - mu; dv.z = xv.z - mu; dv.w = xv.w - mu;
    float vs = dv.x * dv.x + dv.y * dv.y + dv.z * dv.z + dv.w * dv.w;
#pragma unroll
    for (int d = 1; d < 64; d <<= 1) vs += __shfl_xor(vs, d);
    if (lane == 0) red2[wave] = vs;
    __syncthreads();
    const float var = (red2[0] + red2[1] + red2[2] + red2[3]) * (1.0f / 1024.0f);
    const float rs = rsqrtf(var + 1e-5f);
    const float4 g = ((const float4*)gamma)[tid];
    const float4 b = ((const float4*)beta)[tid];
    ushort4 o;
    o.x = f2bf(dv.x * rs * g.x + b.x);
    o.y = f2bf(dv.y * rs * g.y + b.y);
    o.z = f2bf(dv.z * rs * g.z + b.z);
    o.w = f2bf(dv.w * rs * g.w + b.w);
    ((ushort4*)(xn + (size_t)row * 1024))[tid] = o;
    return;
  }

  if (bid >= 128) {  // ---- aux: cvec / bb / rsum-zero ----
    const int b2 = bid - 128;
    if (b2 < 256) {
      if (b2 < 4) {
        const int i2 = (b2 * 256 + tid) * 2;
        ((float4*)rsm)[i2] = make_float4(0.f, 0.f, 0.f, 0.f);
        ((float4*)rsm)[i2 + 1] = make_float4(0.f, 0.f, 0.f, 0.f);
      }
      const int d = b2 * 4 + wave;
      float s = 0.f;
#pragma unroll
      for (int q = 0; q < 2; ++q) {
        ushort8 v = *(const ushort8*)(wkT + (size_t)d * 1024 + lane * 16 + q * 8);
#pragma unroll
        for (int k = 0; k < 8; ++k)
          s += bf2f(v[k]) * bq[lane * 16 + q * 8 + k];
      }
#pragma unroll
      for (int dd = 1; dd < 64; dd <<= 1) s += __shfl_xor(s, dd);
      if (lane == 0) cvec[d] = s * 0.03125f;
    } else {
      const int e = (b2 - 256) * 4 + wave;
      float s = 0.f;
#pragma unroll
      for (int q = 0; q < 4; ++q) {
        float4 a = *(const float4*)(Wo + (size_t)e * 1024 + lane * 16 + q * 4);
        float4 b = *(const float4*)(bv + lane * 16 + q * 4);
        s += a.x * b.x + a.y * b.y + a.z * b.z + a.w * b.w;
      }
#pragma unroll
      for (int dd = 1; dd < 64; dd <<= 1) s += __shfl_xor(s, dd);
      if (lane == 0) bb[e] = s + bo[e];
    }
    return;
  }

  // ---- GEMM: Mt / W4 ----
  const int z = bid >> 6;
  const int idx = bid & 63;
  const int m0 = (idx >> 3) * 128, n0 = (idx & 7) * 128;
  const int wm = (wave >> 1) * 64, wn = (wave & 1) * 64;
  int aOff[4], bOff[4];
  frag_offsets(lane, wm, wn, aOff, bOff);
  f32x4 acc[4][4] = {};
  const unsigned short* a_t = (z == 0) ? (wkT + (size_t)m0 * 1024) : (woB + (size_t)m0 * 1024);
  const unsigned short* b_t = (z == 0) ? (wqT + (size_t)n0 * 1024) : (wvT + (size_t)n0 * 1024);
  gemm_core(a_t, b_t, 1024, 1024, 1024, lds, tid, aOff, bOff, acc);

  const int r0 = (lane >> 4) * 4, cL = lane & 15;
  const float scale = (z == 0) ? 0.03125f : 1.0f;
  unsigned short* Cp = (z == 0) ? mt : w4;
#pragma unroll
  for (int n = 0; n < 4; ++n) {
    int colg = n0 + wn + n * 16 + cL;
#pragma unroll
    for (int m = 0; m < 4; ++m) {
      int rowg = m0 + wm + m * 16 + r0;
#pragma unroll
      for (int i = 0; i < 4; ++i)
        Cp[(size_t)(rowg + i) * 1024 + colg] = f2bf(acc[m][n][i] * scale);
    }
  }
}

// ---------------------------------------------------------------------------
// G1 (dim3(64,8,2) = 1024 blocks, exactly one residency round):
//   z=0: Z = xn @ Mt^T  (LDS-transposed coalesced store)
//   z=1: w_j = xn_j . cvec  (wave per row; flat = by*64+bx < 512)
// Yt moved to g2 (consumed only by g3) for tail-packing.
// ---------------------------------------------------------------------------
__global__ __launch_bounds__(256, 4)
void g1(const unsigned short* __restrict__ xn, const unsigned short* __restrict__ mt,
        unsigned short* __restrict__ Z, const float* __restrict__ cvec,
        float* __restrict__ w)
{
  __shared__ unsigned short lds[16384];
  const int tid = threadIdx.x, lane = tid & 63, wave = tid >> 6;
  const int z = blockIdx.z;

  if (z == 1) {
    const int flat = blockIdx.y * 64 + blockIdx.x;   // 0..511
#pragma unroll
    for (int p = 0; p < 4; ++p) {
      const int j = flat * 16 + wave * 4 + p;
      float s = 0.f;
#pragma unroll
      for (int q = 0; q < 2; ++q) {
        ushort8 v = *(const ushort8*)(xn + (size_t)j * 1024 + lane * 16 + q * 8);
#pragma unroll
        for (int k = 0; k < 8; ++k)
          s += bf2f(v[k]) * cvec[lane * 16 + q * 8 + k];
      }
#pragma unroll
      for (int d = 1; d < 64; d <<= 1) s += __shfl_xor(s, d);
      if (lane == 0) w[j] = s;
    }
    return;
  }

  const int m0 = blockIdx.x * 128, n0 = blockIdx.y * 128;
  const int wm = (wave >> 1) * 64, wn = (wave & 1) * 64;
  int aOff[4], bOff[4];
  frag_offsets(lane, wm, wn, aOff, bOff);
  f32x4 acc[4][4] = {};
  gemm_core(xn + (size_t)m0 * 1024, mt + (size_t)n0 * 1024,
            1024, 1024, 1024, lds, tid, aOff, bOff, acc);

  const int r0 = (lane >> 4) * 4, cL = lane & 15;
  char* lb = (char*)lds;
#pragma unroll
  for (int n = 0; n < 4; ++n) {
    int col_l = wn + n * 16 + cL;
#pragma unroll
    for (int m = 0; m < 4; ++m)
#pragma unroll
      for (int i = 0; i < 4; ++i) {
        int row_l = wm + m * 16 + r0 + i;
        int byte = (row_l * 256 + col_l * 2) ^ ((row_l & 12) << 3);
        *(unsigned short*)(lb + byte) = f2bf(acc[m][n][i]);
      }
  }
  __syncthreads();
  tile_readback(lb, Z + (size_t)m0 * 1024 + n0, 1024, wave, lane);
}

// ---------------------------------------------------------------------------
// G2 (dim3(16,16,6) = 1536 blocks):
//   z<4:  P' = exp(Z[b] @ xn[b]^T + w_col - 12), rsum atomics, S via
//         LDS-transpose coalesced store.
//   z>=4: Yt = (xn @ W4^T)^T per-batch transposed store (flat index; needed
//         only by g3, so packing it here preserves ordering).
// ---------------------------------------------------------------------------
__global__ __launch_bounds__(256, 4)
void g2(const unsigned short* __restrict__ Z, const unsigned short* __restrict__ xn,
        unsigned short* __restrict__ S, const float* __restrict__ w,
        float* __restrict__ rsum, const unsigned short* __restrict__ w4,
        unsigned short* __restrict__ yt)
{
  __shared__ unsigned short lds[16384];
  const int tid = threadIdx.x, lane = tid & 63, wave = tid >> 6;
  const int z = blockIdx.z;
  const int wm = (wave >> 1) * 64, wn = (wave & 1) * 64;
  int aOff[4], bOff[4];
  frag_offsets(lane, wm, wn, aOff, bOff);
  f32x4 acc[4][4] = {};
  const int r0 = (lane >> 4) * 4, cL = lane & 15;

  if (z >= 4) {
    // ---- Yt path ----
    const int flat = (z - 4) * 256 + blockIdx.y * 16 + blockIdx.x;  // 0..511
    const int m0 = (flat >> 3) * 128, n0 = (flat & 7) * 128;
    gemm_core(xn + (size_t)m0 * 1024, w4 + (size_t)n0 * 1024,
              1024, 1024, 1024, lds, tid, aOff, bOff, acc);
#pragma unroll
    for (int n = 0; n < 4; ++n) {
      int colg = n0 + wn + n * 16 + cL;
#pragma unroll
      for (int m = 0; m < 4; ++m) {
        int rowg = m0 + wm + m * 16 + r0;
        int bat = rowg >> 11, sdx = rowg & 2047;
        ushort4 pk;
        pk.x = f2bf(acc[m][n][0]);
        pk.y = f2bf(acc[m][n][1]);
        pk.z = f2bf(acc[m][n][2]);
        pk.w = f2bf(acc[m][n][3]);
        *(ushort4*)(yt + (size_t)bat * 2097152 + (size_t)colg * 2048 + sdx) = pk;
      }
    }
    return;
  }

  // ---- scores path ----
  const int m0 = blockIdx.x * 128, n0 = blockIdx.y * 128;
  gemm_core(Z + (size_t)z * 2097152 + (size_t)m0 * 1024,
            xn + (size_t)z * 2097152 + (size_t)n0 * 1024,
            1024, 1024, 1024, lds, tid, aOff, bOff, acc);

  char* lb = (char*)lds;
  float rs[4][4];
#pragma unroll
  for (int m = 0; m < 4; ++m)
#pragma unroll
    for (int i = 0; i < 4; ++i) rs[m][i] = 0.0f;
#pragma unroll
  for (int n = 0; n < 4; ++n) {
    int col_l = wn + n * 16 + cL;
    float wv = w[(size_t)z * 2048 + n0 + col_l];
#pragma unroll
    for (int m = 0; m < 4; ++m) {
#pragma unroll
      for (int i = 0; i < 4; ++i) {
        int row_l = wm + m * 16 + r0 + i;
        float p = __expf(acc[m][n][i] + wv - 12.0f);
        rs[m][i] += p;
        int byte = (row_l * 256 + col_l * 2) ^ ((row_l & 12) << 3);
        *(unsigned short*)(lb + byte) = f2bf(p);
      }
    }
  }
#pragma unroll
  for (int m = 0; m < 4; ++m)
#pragma unroll
    for (int i = 0; i < 4; ++i) {
      float v = rs[m][i];
      v += __shfl_xor(v, 1);
      v += __shfl_xor(v, 2);
      v += __shfl_xor(v, 4);
      v += __shfl_xor(v, 8);
      if (cL == 0)
        atomicAdd(&rsum[(size_t)z * 2048 + m0 + wm + m * 16 + r0 + i], v);
    }
  __syncthreads();
  tile_readback(lb, S + (size_t)z * 4194304 + (size_t)m0 * 2048 + n0, 2048, wave, lane);
}

// ---------------------------------------------------------------------------
// G3: out[b] = (P'[b] @ Yt[b]^T) / rsum + bb   (fp32, K=2048)
// 64x128 tile -> 1024 blocks = 4/CU.
// ---------------------------------------------------------------------------
__global__ __launch_bounds__(256, 4)
void g3(const unsigned short* __restrict__ S, const unsigned short* __restrict__ yt,
        float* __restrict__ out, const float* __restrict__ bb,
        const float* __restrict__ rsum)
{
  __shared__ unsigned short lds[12288];
  const int tid = threadIdx.x, lane = tid & 63, wave = tid >> 6;
  const int z = blockIdx.z;
  const int m0 = blockIdx.x * 64, n0 = blockIdx.y * 128;
  const int wm = (wave >> 1) * 32, wn = (wave & 1) * 64;

  int aOff[2], bOff[4];
#pragma unroll
  for (int m = 0; m < 2; ++m) {
    int ar = wm + m * 16 + (lane & 15);
    aOff[m] = (ar * 128 + ((lane >> 4) * 16)) ^ ((ar & 7) << 4);
  }
#pragma unroll
  for (int n = 0; n < 4; ++n) {
    int br = wn + n * 16 + (lane & 15);
    bOff[n] = ((br * 128 + ((lane >> 4) * 16)) ^ ((br & 7) << 4)) + 8192;
  }

  const unsigned short* a_t = S + (size_t)z * 4194304 + (size_t)m0 * 2048;
  const unsigned short* b_t = yt + (size_t)z * 2097152 + (size_t)n0 * 2048;

  f32x4 acc[2][4] = {};

  for (int kt = 0; kt < 2048; kt += 64) {
#pragma unroll
    for (int i = 0; i < 2; ++i) {
      int rel = i * 4096 + tid * 16;
      int p = swz(rel);
      int row = p >> 7, ce = (p & 127) >> 1;
      gload16(a_t + (size_t)row * 2048 + (kt + ce), (char*)lds + rel);
    }
#pragma unroll
    for (int i = 0; i < 4; ++i) {
      int rel = i * 4096 + tid * 16;
      int p = swz(rel);
      int row = p >> 7, ce = (p & 127) >> 1;
      gload16(b_t + (size_t)row * 2048 + (kt + ce), (char*)lds + 8192 + rel);
    }
    __syncthreads();
#pragma unroll
    for (int h = 0; h < 2; ++h) {
      bf16x8 av[2], bv4[4];
#pragma unroll
      for (int m = 0; m < 2; ++m)
        av[m] = *(const bf16x8*)((const char*)lds + (aOff[m] ^ (h << 6)));
#pragma unroll
      for (int n = 0; n < 4; ++n)
        bv4[n] = *(const bf16x8*)((const char*)lds + (bOff[n] ^ (h << 6)));
#pragma unroll
      for (int m = 0; m < 2; ++m)
#pragma unroll
        for (int n = 0; n < 4; ++n)
          acc[m][n] = __builtin_amdgcn_mfma_f32_16x16x32_bf16(av[m], bv4[n], acc[m][n], 0, 0, 0);
    }
    __syncthreads();
  }

  const int r0 = (lane >> 4) * 4, cL = lane & 15;
  float* Cp = out + (size_t)z * 2097152;
#pragma unroll
  for (int m = 0; m < 2; ++m) {
    int rowg = m0 + wm + m * 16 + r0;
#pragma unroll
    for (int i = 0; i < 4; ++i) {
      float inv = 1.0f / rsum[(size_t)z * 2048 + rowg + i];
#pragma unroll
      for (int n = 0; n < 4; ++n) {
        int colg = n0 + wn + n * 16 + cL;
        Cp[(size_t)(rowg + i) * 1024 + colg] = acc[m][n][i] * inv + bb[colg];
      }
    }
  }
}

// ---------------------------------------------------------------------------
// prep': weights only. [0,512) Wo cvt; [512,1280) transpose-cvt Wq/Wk/Wv.
// ---------------------------------------------------------------------------
__global__ __launch_bounds__(256)
void prep(const float* __restrict__ Wq, const float* __restrict__ Wk,
          const float* __restrict__ Wv, const float* __restrict__ Wo,
          unsigned short* __restrict__ wqT, unsigned short* __restrict__ wkT,
          unsigned short* __restrict__ wvT, unsigned short* __restrict__ woB)
{
  __shared__ float tlds[64][65];
  const int bid = blockIdx.x;
  const int tid = threadIdx.x;

  if (bid < 512) {
    const int idx = (bid * 256 + tid) * 8;
    const float4 a = *(const float4*)(Wo + idx);
    const float4 b = *(const float4*)(Wo + idx + 4);
    ushort4 r0, r1;
    r0.x = f2bf(a.x); r0.y = f2bf(a.y); r0.z = f2bf(a.z); r0.w = f2bf(a.w);
    r1.x = f2bf(b.x); r1.y = f2bf(b.y); r1.z = f2bf(b.z); r1.w = f2bf(b.w);
    *(ushort4*)(woB + idx) = r0;
    *(ushort4*)(woB + idx + 4) = r1;
    return;
  }
  {
    const int t = bid - 512;
    const int mat = t >> 8;
    const int tile = t & 255;
    const int R0 = (tile >> 4) * 64, C0 = (tile & 15) * 64;
    const float* src = (mat == 0) ? Wq : (mat == 1) ? Wk : Wv;
    unsigned short* dst = (mat == 0) ? wqT : (mat == 1) ? wkT : wvT;
#pragma unroll
    for (int p = 0; p < 4; ++p) {
      int r = p * 16 + (tid >> 4);
      int c = (tid & 15) * 4;
      float4 v = *(const float4*)(src + (size_t)(R0 + r) * 1024 + C0 + c);
      tlds[r][c + 0] = v.x; tlds[r][c + 1] = v.y;
      tlds[r][c + 2] = v.z; tlds[r][c + 3] = v.w;
    }
    __syncthreads();
    const int c = tid >> 2;
    const int chunk = tid & 3;
    ushort8 o0, o1;
#pragma unroll
    for (int k = 0; k < 8; ++k)  o0[k] = f2bf(tlds[chunk * 16 + k][c]);
#pragma unroll
    for (int k = 0; k < 8; ++k)  o1[k] = f2bf(tlds[chunk * 16 + 8 + k][c]);
    unsigned short* dp = dst + (size_t)(C0 + c) * 1024 + R0 + chunk * 16;
    *(ushort8*)(dp) = o0;
    *(ushort8*)(dp + 8) = o1;
  }
}

// ---------------------------------------------------------------------------
extern "C" void kernel_launch(void* const* d_in, const int* in_sizes, int n_in,
                              void* d_out, int out_size, void* d_ws, size_t ws_size,
                              hipStream_t stream) {
  const float* x     = (const float*)d_in[0];
  const float* gamma = (const float*)d_in[1];
  const float* beta  = (const float*)d_in[2];
  const float* Wq    = (const float*)d_in[3];
  const float* bq    = (const float*)d_in[4];
  const float* Wk    = (const float*)d_in[5];
  const float* Wv    = (const float*)d_in[7];
  const float* bv    = (const float*)d_in[8];
  const float* Wo    = (const float*)d_in[9];
  const float* bo    = (const float*)d_in[10];

  char* ws;
  if (ws_size >= (size_t)96542720) {
    ws = (char*)d_ws;
  } else {
    void* sp = nullptr;
    hipGetSymbolAddress(&sp, HIP_SYMBOL(g_scratch));
    ws = (char*)sp;
  }

  unsigned short* xn  = (unsigned short*)(ws);              // 8192x1024 bf16
  unsigned short* Z   = (unsigned short*)(ws + 16777216);   // 8192x1024 bf16
  unsigned short* yt  = (unsigned short*)(ws + 33554432);   // 4x1024x2048 bf16
  unsigned short* S   = (unsigned short*)(ws + 50331648);   // 4x2048x2048 bf16
  unsigned short* wqT = (unsigned short*)(ws + 83886080);
  unsigned short* wkT = (unsigned short*)(ws + 85983232);
  unsigned short* wvT = (unsigned short*)(ws + 88080384);
  unsigned short* woB = (unsigned short*)(ws + 90177536);
  unsigned short* mt  = (unsigned short*)(ws + 92274688);   // (Wk^T Wq)/32
  unsigned short* w4  = (unsigned short*)(ws + 94371840);   // Wo Wv
  float*          wv_ = (float*)(ws + 96468992);            // 8192
  float*          rsm = (float*)(ws + 96501760);            // 8192
  float*          bb  = (float*)(ws + 96534528);            // 1024
  float*          cv  = (float*)(ws + 96538624);            // 1024

  prep<<<1280, 256, 0, stream>>>(Wq, Wk, Wv, Wo, wqT, wkT, wvT, woB);
  g0<<<8832, 256, 0, stream>>>(wkT, wqT, woB, wvT, mt, w4,
                               bq, Wo, bv, bo, cv, bb, rsm,
                               x, gamma, beta, xn);
  g1<<<dim3(64, 8, 2), 256, 0, stream>>>(xn, mt, Z, cv, wv_);
  g2<<<dim3(16, 16, 6), 256, 0, stream>>>(Z, xn, S, wv_, rsm, w4, yt);
  g3<<<dim3(32, 8, 4), 256, 0, stream>>>(S, yt, (float*)d_out, bb, rsm);
}

// Round 17
// 152.442 us; speedup vs baseline: 1.0644x; 1.0570x over previous
//
#include <hip/hip_runtime.h>
#include <hip/hip_bf16.h>
#include <stdint.h>

typedef __attribute__((ext_vector_type(4))) float f32x4;
typedef __attribute__((ext_vector_type(8))) __bf16 bf16x8;
typedef __attribute__((ext_vector_type(8))) unsigned short ushort8;

#define DEV static __device__ __forceinline__

// scratch: xn|Z|Yt|S|WqT|WkT|WvT|Wo|Mt|W4|w|rsum|bb|c  (~96.5 MB)
__device__ __align__(4096) unsigned char g_scratch[96600064];

DEV unsigned short f2bf(float f) {
  union { float f; uint32_t u; } x; x.f = f;
  uint32_t u = x.u;
  uint32_t r = (u + 0x7fffu + ((u >> 16) & 1u)) >> 16;  // RNE
  return (unsigned short)r;
}
DEV float bf2f(unsigned short b) {
  union { uint32_t u; float f; } x; x.u = ((uint32_t)b) << 16;
  return x.f;
}

DEV void gload16(const void* g, void* l) {
  __builtin_amdgcn_global_load_lds((const __attribute__((address_space(1))) void*)g,
                                   (__attribute__((address_space(3))) void*)l,
                                   16, 0, 0);
}

// XOR swizzle on byte offsets within a [rows][128 bytes] region (involution).
DEV int swz(int b) { return b ^ (((b >> 7) & 7) << 4); }

// Verified m97-structure K-loop: 128x128 tile, BK=64, 16x16x32 MFMA,
// swizzled LDS, width-16 global_load_lds. acc[4][4] f32x4 per wave.
DEV void gemm_core(const unsigned short* a_t, const unsigned short* b_t,
                   int ldA, int ldB, int K, unsigned short* lds, int tid,
                   const int* aOff, const int* bOff, f32x4 acc[4][4])
{
  for (int kt = 0; kt < K; kt += 64) {
#pragma unroll
    for (int i = 0; i < 4; ++i) {
      int o = i * 4096 + tid * 16;
      int p = swz(o);
      int row = p >> 7;
      int ce  = (p & 127) >> 1;
      gload16(a_t + (size_t)row * ldA + (kt + ce), (char*)lds + o);
      gload16(b_t + (size_t)row * ldB + (kt + ce), (char*)lds + 16384 + o);
    }
    __syncthreads();
#pragma unroll
    for (int h = 0; h < 2; ++h) {
      bf16x8 av[4], bv4[4];
#pragma unroll
      for (int m = 0; m < 4; ++m)
        av[m] = *(const bf16x8*)((const char*)lds + (aOff[m] ^ (h << 6)));
#pragma unroll
      for (int n = 0; n < 4; ++n)
        bv4[n] = *(const bf16x8*)((const char*)lds + (bOff[n] ^ (h << 6)));
#pragma unroll
      for (int m = 0; m < 4; ++m)
#pragma unroll
        for (int n = 0; n < 4; ++n)
          acc[m][n] = __builtin_amdgcn_mfma_f32_16x16x32_bf16(av[m], bv4[n], acc[m][n], 0, 0, 0);
    }
    __syncthreads();
  }
}

DEV void frag_offsets(int lane, int wm, int wn, int* aOff, int* bOff)
{
#pragma unroll
  for (int m = 0; m < 4; ++m) {
    int ar = wm + m * 16 + (lane & 15);
    aOff[m] = (ar * 128 + ((lane >> 4) * 16)) ^ ((ar & 7) << 4);
    int br = wn + m * 16 + (lane & 15);
    bOff[m] = ((br * 128 + ((lane >> 4) * 16)) ^ ((br & 7) << 4)) + 16384;
  }
}

// Coalesced readback of a 128x128 bf16 tile staged in LDS with
// byte ^= (row&12)<<3 swizzle: each wave stores 32 rows as 256B runs.
DEV void tile_readback(const char* lb, unsigned short* dst, size_t ldC,
                       int wave, int lane)
{
#pragma unroll
  for (int j = 0; j < 8; ++j) {
    int row_l = wave * 32 + (lane >> 4) * 8 + j;
    int byte = (row_l * 256 + (lane & 15) * 16) ^ ((row_l & 12) << 3);
    ushort8 v = *(const ushort8*)(lb + byte);
    *(ushort8*)(dst + (size_t)row_l * ldC + (lane & 15) * 8) = v;
  }
}

// ---------------------------------------------------------------------------
// G0' (8832 blocks, 1-D) -- LN merged in so it overlaps the small GEMM:
//  [0,128):    GEMM  z=b>>6: z=0 Mt=(Wk^T Wq)/32, z=1 W4=Wo Wv
//  [128,384):  cvec[d] = dot(wkT[d,:], bq)/32 (wave/d; blocks 128-131 zero rsum)
//  [384,640):  bb[e] = dot(Wo[e,:], bv) + bo[e]  (wave per e)
//  [640,8832): LayerNorm row (bid-640) -> xn   (no dep on GEMM blocks)
// ---------------------------------------------------------------------------
__global__ __launch_bounds__(256, 4)
void g0(const unsigned short* __restrict__ wkT, const unsigned short* __restrict__ wqT,
        const unsigned short* __restrict__ woB, const unsigned short* __restrict__ wvT,
        unsigned short* __restrict__ mt, unsigned short* __restrict__ w4,
        const float* __restrict__ bq, const float* __restrict__ Wo,
        const float* __restrict__ bv, const float* __restrict__ bo,
        float* __restrict__ cvec, float* __restrict__ bb, float* __restrict__ rsm,
        const float* __restrict__ x, const float* __restrict__ gamma,
        const float* __restrict__ beta, unsigned short* __restrict__ xn)
{
  __shared__ unsigned short lds[16384];
  const int bid = blockIdx.x;
  const int tid = threadIdx.x, lane = tid & 63, wave = tid >> 6;

  if (bid >= 640) {  // ---- LayerNorm row ----
    const int row = bid - 640;
    float* red1 = (float*)lds;
    float* red2 = (float*)lds + 4;
    const float4 xv = ((const float4*)(x + (size_t)row * 1024))[tid];
    float s = xv.x + xv.y + xv.z + xv.w;
#pragma unroll
    for (int d = 1; d < 64; d <<= 1) s += __shfl_xor(s, d);
    if (lane == 0) red1[wave] = s;
    __syncthreads();
    const float mu = (red1[0] + red1[1] + red1[2] + red1[3]) * (1.0f / 1024.0f);
    float4 dv;
    dv.x = xv.x - mu; dv.y = xv.y - mu; dv.z = xv.z - mu; dv.w = xv.w - mu;
    float vs = dv.x * dv.x + dv.y * dv.y + dv.z * dv.z + dv.w * dv.w;
#pragma unroll
    for (int d = 1; d < 64; d <<= 1) vs += __shfl_xor(vs, d);
    if (lane == 0) red2[wave] = vs;
    __syncthreads();
    const float var = (red2[0] + red2[1] + red2[2] + red2[3]) * (1.0f / 1024.0f);
    const float rs = rsqrtf(var + 1e-5f);
    const float4 g = ((const float4*)gamma)[tid];
    const float4 b = ((const float4*)beta)[tid];
    ushort4 o;
    o.x = f2bf(dv.x * rs * g.x + b.x);
    o.y = f2bf(dv.y * rs * g.y + b.y);
    o.z = f2bf(dv.z * rs * g.z + b.z);
    o.w = f2bf(dv.w * rs * g.w + b.w);
    ((ushort4*)(xn + (size_t)row * 1024))[tid] = o;
    return;
  }

  if (bid >= 128) {  // ---- aux: cvec / bb / rsum-zero ----
    const int b2 = bid - 128;
    if (b2 < 256) {
      if (b2 < 4) {
        const int i2 = (b2 * 256 + tid) * 2;
        ((float4*)rsm)[i2] = make_float4(0.f, 0.f, 0.f, 0.f);
        ((float4*)rsm)[i2 + 1] = make_float4(0.f, 0.f, 0.f, 0.f);
      }
      const int d = b2 * 4 + wave;
      float s = 0.f;
#pragma unroll
      for (int q = 0; q < 2; ++q) {
        ushort8 v = *(const ushort8*)(wkT + (size_t)d * 1024 + lane * 16 + q * 8);
#pragma unroll
        for (int k = 0; k < 8; ++k)
          s += bf2f(v[k]) * bq[lane * 16 + q * 8 + k];
      }
#pragma unroll
      for (int dd = 1; dd < 64; dd <<= 1) s += __shfl_xor(s, dd);
      if (lane == 0) cvec[d] = s * 0.03125f;
    } else {
      const int e = (b2 - 256) * 4 + wave;
      float s = 0.f;
#pragma unroll
      for (int q = 0; q < 4; ++q) {
        float4 a = *(const float4*)(Wo + (size_t)e * 1024 + lane * 16 + q * 4);
        float4 b = *(const float4*)(bv + lane * 16 + q * 4);
        s += a.x * b.x + a.y * b.y + a.z * b.z + a.w * b.w;
      }
#pragma unroll
      for (int dd = 1; dd < 64; dd <<= 1) s += __shfl_xor(s, dd);
      if (lane == 0) bb[e] = s + bo[e];
    }
    return;
  }

  // ---- GEMM: Mt / W4 ----
  const int z = bid >> 6;
  const int idx = bid & 63;
  const int m0 = (idx >> 3) * 128, n0 = (idx & 7) * 128;
  const int wm = (wave >> 1) * 64, wn = (wave & 1) * 64;
  int aOff[4], bOff[4];
  frag_offsets(lane, wm, wn, aOff, bOff);
  f32x4 acc[4][4] = {};
  const unsigned short* a_t = (z == 0) ? (wkT + (size_t)m0 * 1024) : (woB + (size_t)m0 * 1024);
  const unsigned short* b_t = (z == 0) ? (wqT + (size_t)n0 * 1024) : (wvT + (size_t)n0 * 1024);
  gemm_core(a_t, b_t, 1024, 1024, 1024, lds, tid, aOff, bOff, acc);

  const int r0 = (lane >> 4) * 4, cL = lane & 15;
  const float scale = (z == 0) ? 0.03125f : 1.0f;
  unsigned short* Cp = (z == 0) ? mt : w4;
#pragma unroll
  for (int n = 0; n < 4; ++n) {
    int colg = n0 + wn + n * 16 + cL;
#pragma unroll
    for (int m = 0; m < 4; ++m) {
      int rowg = m0 + wm + m * 16 + r0;
#pragma unroll
      for (int i = 0; i < 4; ++i)
        Cp[(size_t)(rowg + i) * 1024 + colg] = f2bf(acc[m][n][i] * scale);
    }
  }
}

// ---------------------------------------------------------------------------
// G1: z=0: Z  = xn @ Mt^T  (LDS-transposed coalesced store)
//     z=1: Yt = (xn @ W4^T)^T per-batch store  [= (V-b) Wo^T transposed]
//     z=2: w_j = xn_j . cvec  (wave per row, 512 blocks x 16 rows)
// ---------------------------------------------------------------------------
__global__ __launch_bounds__(256, 4)
void g1(const unsigned short* __restrict__ xn, const unsigned short* __restrict__ mt,
        const unsigned short* __restrict__ w4, unsigned short* __restrict__ Z,
        unsigned short* __restrict__ yt, const float* __restrict__ cvec,
        float* __restrict__ w)
{
  __shared__ unsigned short lds[16384];
  const int tid = threadIdx.x, lane = tid & 63, wave = tid >> 6;
  const int z = blockIdx.z;

  if (z == 2) {
    const int flat = blockIdx.y * 64 + blockIdx.x;   // 0..511
#pragma unroll
    for (int p = 0; p < 4; ++p) {
      const int j = flat * 16 + wave * 4 + p;
      float s = 0.f;
#pragma unroll
      for (int q = 0; q < 2; ++q) {
        ushort8 v = *(const ushort8*)(xn + (size_t)j * 1024 + lane * 16 + q * 8);
#pragma unroll
        for (int k = 0; k < 8; ++k)
          s += bf2f(v[k]) * cvec[lane * 16 + q * 8 + k];
      }
#pragma unroll
      for (int d = 1; d < 64; d <<= 1) s += __shfl_xor(s, d);
      if (lane == 0) w[j] = s;
    }
    return;
  }

  const int m0 = blockIdx.x * 128, n0 = blockIdx.y * 128;
  const int wm = (wave >> 1) * 64, wn = (wave & 1) * 64;
  int aOff[4], bOff[4];
  frag_offsets(lane, wm, wn, aOff, bOff);
  f32x4 acc[4][4] = {};
  const unsigned short* b_t = ((z == 0) ? mt : w4) + (size_t)n0 * 1024;
  gemm_core(xn + (size_t)m0 * 1024, b_t, 1024, 1024, 1024, lds, tid, aOff, bOff, acc);

  const int r0 = (lane >> 4) * 4, cL = lane & 15;
  if (z == 0) {
    char* lb = (char*)lds;
#pragma unroll
    for (int n = 0; n < 4; ++n) {
      int col_l = wn + n * 16 + cL;
#pragma unroll
      for (int m = 0; m < 4; ++m)
#pragma unroll
        for (int i = 0; i < 4; ++i) {
          int row_l = wm + m * 16 + r0 + i;
          int byte = (row_l * 256 + col_l * 2) ^ ((row_l & 12) << 3);
          *(unsigned short*)(lb + byte) = f2bf(acc[m][n][i]);
        }
    }
    __syncthreads();
    tile_readback(lb, Z + (size_t)m0 * 1024 + n0, 1024, wave, lane);
  } else {
#pragma unroll
    for (int n = 0; n < 4; ++n) {
      int colg = n0 + wn + n * 16 + cL;
#pragma unroll
      for (int m = 0; m < 4; ++m) {
        int rowg = m0 + wm + m * 16 + r0;
        int bat = rowg >> 11, sdx = rowg & 2047;
        ushort4 pk;
        pk.x = f2bf(acc[m][n][0]);
        pk.y = f2bf(acc[m][n][1]);
        pk.z = f2bf(acc[m][n][2]);
        pk.w = f2bf(acc[m][n][3]);
        *(ushort4*)(yt + (size_t)bat * 2097152 + (size_t)colg * 2048 + sdx) = pk;
      }
    }
  }
}

// ---------------------------------------------------------------------------
// G2: P' = exp(Z[b] @ xn[b]^T + w_col - 12), row partial sums -> rsum atomics.
// S stored via LDS-transpose for coalesced 256B-run writes.
// ---------------------------------------------------------------------------
__global__ __launch_bounds__(256, 4)
void g2(const unsigned short* __restrict__ Z, const unsigned short* __restrict__ xn,
        unsigned short* __restrict__ S, const float* __restrict__ w,
        float* __restrict__ rsum)
{
  __shared__ unsigned short lds[16384];
  const int tid = threadIdx.x, lane = tid & 63, wave = tid >> 6;
  const int z = blockIdx.z;
  const int m0 = blockIdx.x * 128, n0 = blockIdx.y * 128;
  const int wm = (wave >> 1) * 64, wn = (wave & 1) * 64;
  int aOff[4], bOff[4];
  frag_offsets(lane, wm, wn, aOff, bOff);
  f32x4 acc[4][4] = {};
  gemm_core(Z + (size_t)z * 2097152 + (size_t)m0 * 1024,
            xn + (size_t)z * 2097152 + (size_t)n0 * 1024,
            1024, 1024, 1024, lds, tid, aOff, bOff, acc);

  const int r0 = (lane >> 4) * 4, cL = lane & 15;
  char* lb = (char*)lds;
  float rs[4][4];
#pragma unroll
  for (int m = 0; m < 4; ++m)
#pragma unroll
    for (int i = 0; i < 4; ++i) rs[m][i] = 0.0f;
#pragma unroll
  for (int n = 0; n < 4; ++n) {
    int col_l = wn + n * 16 + cL;
    float wv = w[(size_t)z * 2048 + n0 + col_l];
#pragma unroll
    for (int m = 0; m < 4; ++m) {
#pragma unroll
      for (int i = 0; i < 4; ++i) {
        int row_l = wm + m * 16 + r0 + i;
        float p = __expf(acc[m][n][i] + wv - 12.0f);
        rs[m][i] += p;
        int byte = (row_l * 256 + col_l * 2) ^ ((row_l & 12) << 3);
        *(unsigned short*)(lb + byte) = f2bf(p);
      }
    }
  }
#pragma unroll
  for (int m = 0; m < 4; ++m)
#pragma unroll
    for (int i = 0; i < 4; ++i) {
      float v = rs[m][i];
      v += __shfl_xor(v, 1);
      v += __shfl_xor(v, 2);
      v += __shfl_xor(v, 4);
      v += __shfl_xor(v, 8);
      if (cL == 0)
        atomicAdd(&rsum[(size_t)z * 2048 + m0 + wm + m * 16 + r0 + i], v);
    }
  __syncthreads();
  tile_readback(lb, S + (size_t)z * 4194304 + (size_t)m0 * 2048 + n0, 2048, wave, lane);
}

// ---------------------------------------------------------------------------
// G3: out[b] = (P'[b] @ Yt[b]^T) / rsum + bb   (fp32, K=2048)
// 64x128 tile -> 1024 blocks = 4/CU.
// ---------------------------------------------------------------------------
__global__ __launch_bounds__(256, 4)
void g3(const unsigned short* __restrict__ S, const unsigned short* __restrict__ yt,
        float* __restrict__ out, const float* __restrict__ bb,
        const float* __restrict__ rsum)
{
  __shared__ unsigned short lds[12288];
  const int tid = threadIdx.x, lane = tid & 63, wave = tid >> 6;
  const int z = blockIdx.z;
  const int m0 = blockIdx.x * 64, n0 = blockIdx.y * 128;
  const int wm = (wave >> 1) * 32, wn = (wave & 1) * 64;

  int aOff[2], bOff[4];
#pragma unroll
  for (int m = 0; m < 2; ++m) {
    int ar = wm + m * 16 + (lane & 15);
    aOff[m] = (ar * 128 + ((lane >> 4) * 16)) ^ ((ar & 7) << 4);
  }
#pragma unroll
  for (int n = 0; n < 4; ++n) {
    int br = wn + n * 16 + (lane & 15);
    bOff[n] = ((br * 128 + ((lane >> 4) * 16)) ^ ((br & 7) << 4)) + 8192;
  }

  const unsigned short* a_t = S + (size_t)z * 4194304 + (size_t)m0 * 2048;
  const unsigned short* b_t = yt + (size_t)z * 2097152 + (size_t)n0 * 2048;

  f32x4 acc[2][4] = {};

  for (int kt = 0; kt < 2048; kt += 64) {
#pragma unroll
    for (int i = 0; i < 2; ++i) {
      int rel = i * 4096 + tid * 16;
      int p = swz(rel);
      int row = p >> 7, ce = (p & 127) >> 1;
      gload16(a_t + (size_t)row * 2048 + (kt + ce), (char*)lds + rel);
    }
#pragma unroll
    for (int i = 0; i < 4; ++i) {
      int rel = i * 4096 + tid * 16;
      int p = swz(rel);
      int row = p >> 7, ce = (p & 127) >> 1;
      gload16(b_t + (size_t)row * 2048 + (kt + ce), (char*)lds + 8192 + rel);
    }
    __syncthreads();
#pragma unroll
    for (int h = 0; h < 2; ++h) {
      bf16x8 av[2], bv4[4];
#pragma unroll
      for (int m = 0; m < 2; ++m)
        av[m] = *(const bf16x8*)((const char*)lds + (aOff[m] ^ (h << 6)));
#pragma unroll
      for (int n = 0; n < 4; ++n)
        bv4[n] = *(const bf16x8*)((const char*)lds + (bOff[n] ^ (h << 6)));
#pragma unroll
      for (int m = 0; m < 2; ++m)
#pragma unroll
        for (int n = 0; n < 4; ++n)
          acc[m][n] = __builtin_amdgcn_mfma_f32_16x16x32_bf16(av[m], bv4[n], acc[m][n], 0, 0, 0);
    }
    __syncthreads();
  }

  const int r0 = (lane >> 4) * 4, cL = lane & 15;
  float* Cp = out + (size_t)z * 2097152;
#pragma unroll
  for (int m = 0; m < 2; ++m) {
    int rowg = m0 + wm + m * 16 + r0;
#pragma unroll
    for (int i = 0; i < 4; ++i) {
      float inv = 1.0f / rsum[(size_t)z * 2048 + rowg + i];
#pragma unroll
      for (int n = 0; n < 4; ++n) {
        int colg = n0 + wn + n * 16 + cL;
        Cp[(size_t)(rowg + i) * 1024 + colg] = acc[m][n][i] * inv + bb[colg];
      }
    }
  }
}

// ---------------------------------------------------------------------------
// prep': weights only. [0,512) Wo cvt; [512,1280) transpose-cvt Wq/Wk/Wv.
// ---------------------------------------------------------------------------
__global__ __launch_bounds__(256)
void prep(const float* __restrict__ Wq, const float* __restrict__ Wk,
          const float* __restrict__ Wv, const float* __restrict__ Wo,
          unsigned short* __restrict__ wqT, unsigned short* __restrict__ wkT,
          unsigned short* __restrict__ wvT, unsigned short* __restrict__ woB)
{
  __shared__ float tlds[64][65];
  const int bid = blockIdx.x;
  const int tid = threadIdx.x;

  if (bid < 512) {
    const int idx = (bid * 256 + tid) * 8;
    const float4 a = *(const float4*)(Wo + idx);
    const float4 b = *(const float4*)(Wo + idx + 4);
    ushort4 r0, r1;
    r0.x = f2bf(a.x); r0.y = f2bf(a.y); r0.z = f2bf(a.z); r0.w = f2bf(a.w);
    r1.x = f2bf(b.x); r1.y = f2bf(b.y); r1.z = f2bf(b.z); r1.w = f2bf(b.w);
    *(ushort4*)(woB + idx) = r0;
    *(ushort4*)(woB + idx + 4) = r1;
    return;
  }
  {
    const int t = bid - 512;
    const int mat = t >> 8;
    const int tile = t & 255;
    const int R0 = (tile >> 4) * 64, C0 = (tile & 15) * 64;
    const float* src = (mat == 0) ? Wq : (mat == 1) ? Wk : Wv;
    unsigned short* dst = (mat == 0) ? wqT : (mat == 1) ? wkT : wvT;
#pragma unroll
    for (int p = 0; p < 4; ++p) {
      int r = p * 16 + (tid >> 4);
      int c = (tid & 15) * 4;
      float4 v = *(const float4*)(src + (size_t)(R0 + r) * 1024 + C0 + c);
      tlds[r][c + 0] = v.x; tlds[r][c + 1] = v.y;
      tlds[r][c + 2] = v.z; tlds[r][c + 3] = v.w;
    }
    __syncthreads();
    const int c = tid >> 2;
    const int chunk = tid & 3;
    ushort8 o0, o1;
#pragma unroll
    for (int k = 0; k < 8; ++k)  o0[k] = f2bf(tlds[chunk * 16 + k][c]);
#pragma unroll
    for (int k = 0; k < 8; ++k)  o1[k] = f2bf(tlds[chunk * 16 + 8 + k][c]);
    unsigned short* dp = dst + (size_t)(C0 + c) * 1024 + R0 + chunk * 16;
    *(ushort8*)(dp) = o0;
    *(ushort8*)(dp + 8) = o1;
  }
}

// ---------------------------------------------------------------------------
extern "C" void kernel_launch(void* const* d_in, const int* in_sizes, int n_in,
                              void* d_out, int out_size, void* d_ws, size_t ws_size,
                              hipStream_t stream) {
  const float* x     = (const float*)d_in[0];
  const float* gamma = (const float*)d_in[1];
  const float* beta  = (const float*)d_in[2];
  const float* Wq    = (const float*)d_in[3];
  const float* bq    = (const float*)d_in[4];
  const float* Wk    = (const float*)d_in[5];
  const float* Wv    = (const float*)d_in[7];
  const float* bv    = (const float*)d_in[8];
  const float* Wo    = (const float*)d_in[9];
  const float* bo    = (const float*)d_in[10];

  char* ws;
  if (ws_size >= (size_t)96542720) {
    ws = (char*)d_ws;
  } else {
    void* sp = nullptr;
    hipGetSymbolAddress(&sp, HIP_SYMBOL(g_scratch));
    ws = (char*)sp;
  }

  unsigned short* xn  = (unsigned short*)(ws);              // 8192x1024 bf16
  unsigned short* Z   = (unsigned short*)(ws + 16777216);   // 8192x1024 bf16
  unsigned short* yt  = (unsigned short*)(ws + 33554432);   // 4x1024x2048 bf16
  unsigned short* S   = (unsigned short*)(ws + 50331648);   // 4x2048x2048 bf16
  unsigned short* wqT = (unsigned short*)(ws + 83886080);
  unsigned short* wkT = (unsigned short*)(ws + 85983232);
  unsigned short* wvT = (unsigned short*)(ws + 88080384);
  unsigned short* woB = (unsigned short*)(ws + 90177536);
  unsigned short* mt  = (unsigned short*)(ws + 92274688);   // (Wk^T Wq)/32
  unsigned short* w4  = (unsigned short*)(ws + 94371840);   // Wo Wv
  float*          wv_ = (float*)(ws + 96468992);            // 8192
  float*          rsm = (float*)(ws + 96501760);            // 8192
  float*          bb  = (float*)(ws + 96534528);            // 1024
  float*          cv  = (float*)(ws + 96538624);            // 1024

  prep<<<1280, 256, 0, stream>>>(Wq, Wk, Wv, Wo, wqT, wkT, wvT, woB);
  g0<<<8832, 256, 0, stream>>>(wkT, wqT, woB, wvT, mt, w4,
                               bq, Wo, bv, bo, cv, bb, rsm,
                               x, gamma, beta, xn);
  g1<<<dim3(64, 8, 3), 256, 0, stream>>>(xn, mt, w4, Z, yt, cv, wv_);
  g2<<<dim3(16, 16, 4), 256, 0, stream>>>(Z, xn, S, wv_, rsm);
  g3<<<dim3(32, 8, 4), 256, 0, stream>>>(S, yt, (float*)d_out, bb, rsm);
}